// Round 4
// baseline (436.604 us; speedup 1.0000x reference)
//
#include <hip/hip_runtime.h>

#define NN 400000
#define NE 400000

typedef __attribute__((ext_vector_type(4))) float f32x4;
typedef __attribute__((ext_vector_type(8))) short s16x8;
typedef unsigned short ushort_t;

__device__ __forceinline__ ushort_t f2bf(float f) {
    union { float f; unsigned int u; } c;
    c.f = f;
    unsigned int u = c.u;
    u = u + 0x7fffu + ((u >> 16) & 1u);
    return (ushort_t)(u >> 16);
}
__device__ __forceinline__ float bf2f(ushort_t v) {
    union { unsigned int u; float f; } c;
    c.u = ((unsigned int)v) << 16;
    return c.f;
}

// --- detect whether edge_index arrived as int64 (odd 32-bit words all zero) ---
__global__ void k_detect(const int* __restrict__ ei_raw, int* __restrict__ flag) {
    if (threadIdx.x == 0 && blockIdx.x == 0) {
        int is64 = 1;
        for (int i = 0; i < 64; i++)
            if (ei_raw[2 * i + 1] != 0) { is64 = 0; break; }
        flag[0] = is64;
    }
}

__global__ void k_cvt_idx(const int* __restrict__ ei_raw, const int* __restrict__ flag,
                          int* __restrict__ ei32) {
    const int i = blockIdx.x * 256 + threadIdx.x;
    const int f = flag[0];
    ei32[i] = f ? ei_raw[2 * i] : ei_raw[i];
}

// --- W [128,512] f32 -> bf16, plain row-major (B frags are register-loaded now) ---
__global__ void k_wcvt(const float* __restrict__ W, ushort_t* __restrict__ wbf) {
    const int i = blockIdx.x * 256 + threadIdx.x;
    wbf[i] = f2bf(W[i]);
}

// --- fused: per-node u,v scores + x -> bf16 conversion (unchanged) ---
__global__ void k_uv_cvt(const float* __restrict__ x, const float* __restrict__ att,
                         ushort_t* __restrict__ xbf, float* __restrict__ uv) {
    const int lane = threadIdx.x & 63;
    const int wid = threadIdx.x >> 6;
    const int g = lane & 15;
    const int ns = lane >> 4;

    float areg[8][8];
#pragma unroll
    for (int h = 0; h < 4; h++) {
        const f32x4 fa = *(const f32x4*)(att + h * 256 + g * 8);
        const f32x4 fb = *(const f32x4*)(att + h * 256 + g * 8 + 4);
        const f32x4 ba = *(const f32x4*)(att + h * 256 + 128 + g * 8);
        const f32x4 bb = *(const f32x4*)(att + h * 256 + 128 + g * 8 + 4);
#pragma unroll
        for (int m = 0; m < 4; m++) {
            areg[h][m] = fa[m];     areg[h][4 + m] = fb[m];
            areg[4 + h][m] = ba[m]; areg[4 + h][4 + m] = bb[m];
        }
    }

    for (int tile = blockIdx.x; tile < NN / 32; tile += gridDim.x) {
        const int nb = tile * 32 + wid * 8 + ns;
#pragma unroll
        for (int t = 0; t < 2; t++) {
            const int n = nb + t * 4;
            const f32x4 xa = *(const f32x4*)(x + (size_t)n * 128 + g * 8);
            const f32x4 xb = *(const f32x4*)(x + (size_t)n * 128 + g * 8 + 4);
            s16x8 pk;
#pragma unroll
            for (int m = 0; m < 4; m++) { pk[m] = (short)f2bf(xa[m]); pk[4 + m] = (short)f2bf(xb[m]); }
            *(s16x8*)(xbf + (size_t)n * 128 + g * 8) = pk;
            float r[8];
#pragma unroll
            for (int v = 0; v < 8; v++) {
                float s = 0.f;
#pragma unroll
                for (int m = 0; m < 4; m++) s += xa[m] * areg[v][m];
#pragma unroll
                for (int m = 0; m < 4; m++) s += xb[m] * areg[v][4 + m];
                r[v] = s;
            }
#pragma unroll
            for (int mask = 1; mask <= 4; mask <<= 1)
#pragma unroll
                for (int v = 0; v < 8; v++) r[v] += __shfl_xor(r[v], mask, 64);
            const int gv = g & 7;
            float s = r[0];
#pragma unroll
            for (int v = 1; v < 8; v++) s = (gv == v) ? r[v] : s;
            s += __shfl_xor(s, 8, 64);
            if (g < 8) uv[(size_t)n * 8 + g] = s;
        }
    }
}

// --- per-edge: leaky_relu -> head softmax -> p=exp(score), atomic denom ---
__global__ void k_edge(const int* __restrict__ ei, const float* __restrict__ uv,
                       float* __restrict__ p, float* __restrict__ denom) {
    const int e = blockIdx.x * 256 + threadIdx.x;
    if (e >= NE) return;
    const int row = ei[e];
    const int col = ei[NE + e];
    const f32x4 u = *(const f32x4*)(uv + (size_t)row * 8);
    const f32x4 v = *(const f32x4*)(uv + (size_t)col * 8 + 4);
    float s[4];
    float mx = -1e30f;
#pragma unroll
    for (int h = 0; h < 4; h++) {
        float t = u[h] + v[h];
        t = t > 0.f ? t : 0.01f * t;
        s[h] = t;
        mx = fmaxf(mx, t);
    }
    float ex[4], sum = 0.f;
#pragma unroll
    for (int h = 0; h < 4; h++) { ex[h] = __expf(s[h] - mx); sum += ex[h]; }
    const float inv = 1.f / sum;
    f32x4 pv;
#pragma unroll
    for (int h = 0; h < 4; h++) pv[h] = __expf(ex[h] * inv);
    *(f32x4*)(p + (size_t)e * 4) = pv;
#pragma unroll
    for (int h = 0; h < 4; h++) atomicAdd(denom + (size_t)row * 4 + h, pv[h]);
}

// --- alpha_t[h][e] = p[e,h] / denom[row[e],h]  (transposed planes) ---
__global__ void k_alpha(const int* __restrict__ ei, const float* __restrict__ p,
                        const float* __restrict__ denom, float* __restrict__ alpha_t) {
    const int e = blockIdx.x * 256 + threadIdx.x;
    if (e >= NE) return;
    const int row = ei[e];
    const f32x4 pv = *(const f32x4*)(p + (size_t)e * 4);
    const f32x4 dv = *(const f32x4*)(denom + (size_t)row * 4);
#pragma unroll
    for (int h = 0; h < 4; h++) alpha_t[(size_t)h * NE + e] = pv[h] / dv[h];
}

// --- barrier-free head-split GEMM.
//     Block: 800 edges x 128 cols, 8 waves; wave owns 16 cols (wid*16..+16).
//     B (all heads, full K) lives in 64 VGPRs per wave, loaded once.
//     A frags gathered global->reg directly in MFMA layout; 2-deep reg pipeline.
//     LDS: only col idx + alpha staging (16 KB). Zero barriers in main loop. ---
__global__ __launch_bounds__(512, 2) void k_gemm(
    const ushort_t* __restrict__ xbf, const int* __restrict__ ei,
    const float* __restrict__ alpha_t, const ushort_t* __restrict__ wbf,
    const float* __restrict__ bias, float* __restrict__ out)
{
    __shared__ int col_s[800];
    __shared__ float alp_s[4][800];

    const int tid = threadIdx.x;
    const int lane = tid & 63;
    const int wid = tid >> 6;
    const int e0 = blockIdx.x * 800;

    // stage col indices + alpha planes for this block's 800 edges
    for (int j = tid; j < 800; j += 512) col_s[j] = ei[NE + e0 + j];
#pragma unroll
    for (int h = 0; h < 4; h++)
        for (int j = tid; j < 800; j += 512) alp_s[h][j] = alpha_t[(size_t)h * NE + e0 + j];

    // B fragments in registers: bfr[h][ks], lane l = col row (lane&15), 8 elems at (lane>>4)*8
    s16x8 bfr[4][4];
    {
        const ushort_t* bbase = wbf + (wid * 16 + (lane & 15)) * 512 + (lane >> 4) * 8;
#pragma unroll
        for (int h = 0; h < 4; h++)
#pragma unroll
            for (int ks = 0; ks < 4; ks++)
                bfr[h][ks] = *(const s16x8*)(bbase + h * 128 + ks * 32);
    }
    const float bias_r = bias[wid * 16 + (lane & 15)];
    __syncthreads();

    const f32x4 zero = {0.f, 0.f, 0.f, 0.f};
    s16x8 afA[2][4], afB[2][4];

    auto LOADA = [&](int t, s16x8 (&af)[2][4]) {
#pragma unroll
        for (int eb = 0; eb < 2; eb++) {
            const int c = col_s[t * 32 + eb * 16 + (lane & 15)];
            const ushort_t* base = xbf + (size_t)c * 128 + (lane >> 4) * 8;
#pragma unroll
            for (int jq = 0; jq < 4; jq++)
                af[eb][jq] = *(const s16x8*)(base + jq * 32);
        }
    };

    auto TILE = [&](int t, s16x8 (&af)[2][4]) {
        f32x4 fin0 = zero, fin1 = zero;
#pragma unroll
        for (int h = 0; h < 4; h++) {
            f32x4 a0 = __builtin_amdgcn_mfma_f32_16x16x32_bf16(af[0][0], bfr[h][0], zero, 0, 0, 0);
            f32x4 a1 = __builtin_amdgcn_mfma_f32_16x16x32_bf16(af[1][0], bfr[h][0], zero, 0, 0, 0);
#pragma unroll
            for (int ks = 1; ks < 4; ks++) {
                a0 = __builtin_amdgcn_mfma_f32_16x16x32_bf16(af[0][ks], bfr[h][ks], a0, 0, 0, 0);
                a1 = __builtin_amdgcn_mfma_f32_16x16x32_bf16(af[1][ks], bfr[h][ks], a1, 0, 0, 0);
            }
            const f32x4 av0 = *(const f32x4*)&alp_s[h][t * 32 + (lane >> 4) * 4];
            const f32x4 av1 = *(const f32x4*)&alp_s[h][t * 32 + 16 + (lane >> 4) * 4];
            fin0 += av0 * a0;
            fin1 += av1 * a1;
        }
        const int i = wid * 16 + (lane & 15);
#pragma unroll
        for (int r = 0; r < 4; r++) {
            {
                const int e = e0 + t * 32 + (lane >> 4) * 4 + r;
                const size_t off = (size_t)e * 128 + i;
                out[off] = fin0[r] + bias_r + bf2f(xbf[off]);
            }
            {
                const int e = e0 + t * 32 + 16 + (lane >> 4) * 4 + r;
                const size_t off = (size_t)e * 128 + i;
                out[off] = fin1[r] + bias_r + bf2f(xbf[off]);
            }
        }
    };

    // 25 tiles of 32 edges; software pipeline with named double-buffer (static indexing)
    LOADA(0, afA);
#pragma unroll 1
    for (int t = 0; t < 25; t += 2) {
        if (t + 1 < 25) LOADA(t + 1, afB);
        TILE(t, afA);
        if (t + 1 < 25) {
            if (t + 2 < 25) LOADA(t + 2, afA);
            TILE(t + 1, afB);
        }
    }
}

extern "C" void kernel_launch(void* const* d_in, const int* in_sizes, int n_in,
                              void* d_out, int out_size, void* d_ws, size_t ws_size,
                              hipStream_t stream) {
    const float* x      = (const float*)d_in[0];
    const int*   ei_raw = (const int*)d_in[1];
    const float* att    = (const float*)d_in[2];
    const float* W      = (const float*)d_in[3];
    const float* b      = (const float*)d_in[4];
    float* out = (float*)d_out;

    char* ws = (char*)d_ws;
    float*    uv      = (float*)(ws);                     // N*8 f32   = 12.8 MB
    float*    p       = (float*)(ws + 12800000);          // E*4 f32   =  6.4 MB
    float*    denom   = (float*)(ws + 19200000);          // N*4 f32   =  6.4 MB
    float*    alpha_t = (float*)(ws + 25600000);          // 4 planes  =  6.4 MB
    ushort_t* wbf     = (ushort_t*)(ws + 32000000);       // 128 KB
    int*      flag    = (int*)(ws + 32200000);            // 4 B
    int*      ei32    = (int*)(ws + 32200064);            // 3.2 MB
    ushort_t* xbf     = (ushort_t*)(ws + 35400192);       // N*128 bf16 = 102.4 MB

    hipMemsetAsync(denom, 0, (size_t)NN * 4 * sizeof(float), stream);
    k_detect<<<1, 64, 0, stream>>>(ei_raw, flag);
    k_cvt_idx<<<2 * NE / 256, 256, 0, stream>>>(ei_raw, flag, ei32);
    k_wcvt<<<256, 256, 0, stream>>>(W, wbf);
    k_uv_cvt<<<2048, 256, 0, stream>>>(x, att, xbf, uv);
    k_edge<<<(NE + 255) / 256, 256, 0, stream>>>(ei32, uv, p, denom);
    k_alpha<<<(NE + 255) / 256, 256, 0, stream>>>(ei32, p, denom, alpha_t);
    k_gemm<<<NE / 800, 512, 0, stream>>>(xbf, ei32, alpha_t, wbf, b, out);
}

// Round 5
// 302.091 us; speedup vs baseline: 1.4453x; 1.4453x over previous
//
#include <hip/hip_runtime.h>

#define NN 400000
#define NE 400000

typedef __attribute__((ext_vector_type(4))) float f32x4;
typedef __attribute__((ext_vector_type(8))) short s16x8;
typedef unsigned short ushort_t;

__device__ __forceinline__ ushort_t f2bf(float f) {
    union { float f; unsigned int u; } c;
    c.f = f;
    unsigned int u = c.u;
    u = u + 0x7fffu + ((u >> 16) & 1u);
    return (ushort_t)(u >> 16);
}
__device__ __forceinline__ float bf2f(ushort_t v) {
    union { unsigned int u; float f; } c;
    c.u = ((unsigned int)v) << 16;
    return c.f;
}

// --- detect whether edge_index arrived as int64 (odd 32-bit words all zero) ---
__global__ void k_detect(const int* __restrict__ ei_raw, int* __restrict__ flag) {
    if (threadIdx.x == 0 && blockIdx.x == 0) {
        int is64 = 1;
        for (int i = 0; i < 64; i++)
            if (ei_raw[2 * i + 1] != 0) { is64 = 0; break; }
        flag[0] = is64;
    }
}

__global__ void k_cvt_idx(const int* __restrict__ ei_raw, const int* __restrict__ flag,
                          int* __restrict__ ei32) {
    const int i = blockIdx.x * 256 + threadIdx.x;
    const int f = flag[0];
    ei32[i] = f ? ei_raw[2 * i] : ei_raw[i];
}

// --- W [128,512] f32 -> bf16, plain row-major ---
__global__ void k_wcvt(const float* __restrict__ W, ushort_t* __restrict__ wbf) {
    const int i = blockIdx.x * 256 + threadIdx.x;
    wbf[i] = f2bf(W[i]);
}

// --- fused: per-node u,v scores + x -> bf16 conversion (unchanged from r3) ---
__global__ void k_uv_cvt(const float* __restrict__ x, const float* __restrict__ att,
                         ushort_t* __restrict__ xbf, float* __restrict__ uv) {
    const int lane = threadIdx.x & 63;
    const int wid = threadIdx.x >> 6;
    const int g = lane & 15;
    const int ns = lane >> 4;

    float areg[8][8];
#pragma unroll
    for (int h = 0; h < 4; h++) {
        const f32x4 fa = *(const f32x4*)(att + h * 256 + g * 8);
        const f32x4 fb = *(const f32x4*)(att + h * 256 + g * 8 + 4);
        const f32x4 ba = *(const f32x4*)(att + h * 256 + 128 + g * 8);
        const f32x4 bb = *(const f32x4*)(att + h * 256 + 128 + g * 8 + 4);
#pragma unroll
        for (int m = 0; m < 4; m++) {
            areg[h][m] = fa[m];     areg[h][4 + m] = fb[m];
            areg[4 + h][m] = ba[m]; areg[4 + h][4 + m] = bb[m];
        }
    }

    for (int tile = blockIdx.x; tile < NN / 32; tile += gridDim.x) {
        const int nb = tile * 32 + wid * 8 + ns;
#pragma unroll
        for (int t = 0; t < 2; t++) {
            const int n = nb + t * 4;
            const f32x4 xa = *(const f32x4*)(x + (size_t)n * 128 + g * 8);
            const f32x4 xb = *(const f32x4*)(x + (size_t)n * 128 + g * 8 + 4);
            s16x8 pk;
#pragma unroll
            for (int m = 0; m < 4; m++) { pk[m] = (short)f2bf(xa[m]); pk[4 + m] = (short)f2bf(xb[m]); }
            *(s16x8*)(xbf + (size_t)n * 128 + g * 8) = pk;
            float r[8];
#pragma unroll
            for (int v = 0; v < 8; v++) {
                float s = 0.f;
#pragma unroll
                for (int m = 0; m < 4; m++) s += xa[m] * areg[v][m];
#pragma unroll
                for (int m = 0; m < 4; m++) s += xb[m] * areg[v][4 + m];
                r[v] = s;
            }
#pragma unroll
            for (int mask = 1; mask <= 4; mask <<= 1)
#pragma unroll
                for (int v = 0; v < 8; v++) r[v] += __shfl_xor(r[v], mask, 64);
            const int gv = g & 7;
            float s = r[0];
#pragma unroll
            for (int v = 1; v < 8; v++) s = (gv == v) ? r[v] : s;
            s += __shfl_xor(s, 8, 64);
            if (g < 8) uv[(size_t)n * 8 + g] = s;
        }
    }
}

// --- per-edge: leaky_relu -> head softmax -> p=exp(score), atomic denom ---
__global__ void k_edge(const int* __restrict__ ei, const float* __restrict__ uv,
                       float* __restrict__ p, float* __restrict__ denom) {
    const int e = blockIdx.x * 256 + threadIdx.x;
    if (e >= NE) return;
    const int row = ei[e];
    const int col = ei[NE + e];
    const f32x4 u = *(const f32x4*)(uv + (size_t)row * 8);
    const f32x4 v = *(const f32x4*)(uv + (size_t)col * 8 + 4);
    float s[4];
    float mx = -1e30f;
#pragma unroll
    for (int h = 0; h < 4; h++) {
        float t = u[h] + v[h];
        t = t > 0.f ? t : 0.01f * t;
        s[h] = t;
        mx = fmaxf(mx, t);
    }
    float ex[4], sum = 0.f;
#pragma unroll
    for (int h = 0; h < 4; h++) { ex[h] = __expf(s[h] - mx); sum += ex[h]; }
    const float inv = 1.f / sum;
    f32x4 pv;
#pragma unroll
    for (int h = 0; h < 4; h++) pv[h] = __expf(ex[h] * inv);
    *(f32x4*)(p + (size_t)e * 4) = pv;
#pragma unroll
    for (int h = 0; h < 4; h++) atomicAdd(denom + (size_t)row * 4 + h, pv[h]);
}

// --- hybrid head-split GEMM.
//     Block: 128 edges x 128 cols, 4 waves; wave owns 32 cols (2 col-blocks).
//     A staged ONCE in LDS (balanced XOR swizzle (row&15)<<4), shared by all waves.
//     B (4 heads x K=128 x 32 cols) in 128 VGPRs per wave, loaded once.
//     alpha computed inline from p/denom into 2KB LDS.
//     ONE barrier total; zero barriers in main loop. ---
__global__ __launch_bounds__(256) void k_gemm(
    const ushort_t* __restrict__ xbf, const int* __restrict__ ei,
    const float* __restrict__ p, const float* __restrict__ denom,
    const ushort_t* __restrict__ wbf, const float* __restrict__ bias,
    float* __restrict__ out)
{
    __shared__ __align__(16) ushort_t Asm[128 * 128];  // [e][k] bf16, 256B rows, swz (e&15)<<4
    __shared__ __align__(16) float alp_s[4][128];

    const int tid = threadIdx.x;
    const int lane = tid & 63;
    const int w = tid >> 6;          // wave: cols w*32..w*32+32
    const int e0 = blockIdx.x * 128;

    // A stage: each thread stages 128B of one edge row (gather 1x, reg->swizzled LDS)
    {
        const int e_loc = tid >> 1, half = tid & 1;
        const int col = ei[NE + e0 + e_loc];
        const ushort_t* src = xbf + (size_t)col * 128 + half * 64;
#pragma unroll
        for (int q = 0; q < 8; q++) {
            const s16x8 v = *(const s16x8*)(src + q * 8);
            const int byte = e_loc * 256 + ((half * 128 + q * 16) ^ ((e_loc & 15) << 4));
            *(s16x8*)((char*)Asm + byte) = v;
        }
    }
    // alpha inline: alp_s[h][e] = p[e,h] / denom[row[e],h]
    if (tid < 128) {
        const int e = e0 + tid;
        const int row = ei[e];
        const f32x4 pv = *(const f32x4*)(p + (size_t)e * 4);
        const f32x4 dv = *(const f32x4*)(denom + (size_t)row * 4);
#pragma unroll
        for (int h = 0; h < 4; h++) alp_s[h][tid] = pv[h] / dv[h];
    }
    // B fragments in registers: bfr[h][ks][cb], lane row i=(lane&15), k8 group (lane>>4)
    s16x8 bfr[4][4][2];
#pragma unroll
    for (int cb = 0; cb < 2; cb++) {
        const ushort_t* bbase = wbf + (size_t)(w * 32 + cb * 16 + (lane & 15)) * 512 + (lane >> 4) * 8;
#pragma unroll
        for (int h = 0; h < 4; h++)
#pragma unroll
            for (int ks = 0; ks < 4; ks++)
                bfr[h][ks][cb] = *(const s16x8*)(bbase + h * 128 + ks * 32);
    }
    float bias_r[2];
#pragma unroll
    for (int cb = 0; cb < 2; cb++) bias_r[cb] = bias[w * 32 + cb * 16 + (lane & 15)];

    __syncthreads();   // A + alpha ready; no further barriers

    const f32x4 zero = {0.f, 0.f, 0.f, 0.f};

#pragma unroll 1
    for (int t = 0; t < 4; t++) {
        // A fragments from LDS (balanced swizzle -> throughput-floor reads)
        s16x8 af[2][4];
#pragma unroll
        for (int eb = 0; eb < 2; eb++) {
            const int rr = t * 32 + eb * 16 + (lane & 15);
#pragma unroll
            for (int ks = 0; ks < 4; ks++) {
                const int byte = rr * 256 + ((ks * 64 + (lane >> 4) * 16) ^ ((rr & 15) << 4));
                af[eb][ks] = *(const s16x8*)((const char*)Asm + byte);
            }
        }
        f32x4 fin[2][2];
#pragma unroll
        for (int eb = 0; eb < 2; eb++)
#pragma unroll
            for (int cb = 0; cb < 2; cb++) fin[eb][cb] = zero;

#pragma unroll
        for (int h = 0; h < 4; h++) {
            f32x4 av[2];
#pragma unroll
            for (int eb = 0; eb < 2; eb++)
                av[eb] = *(const f32x4*)&alp_s[h][t * 32 + eb * 16 + (lane >> 4) * 4];
#pragma unroll
            for (int eb = 0; eb < 2; eb++)
#pragma unroll
                for (int cb = 0; cb < 2; cb++) {
                    f32x4 a = __builtin_amdgcn_mfma_f32_16x16x32_bf16(af[eb][0], bfr[h][0][cb], zero, 0, 0, 0);
#pragma unroll
                    for (int ks = 1; ks < 4; ks++)
                        a = __builtin_amdgcn_mfma_f32_16x16x32_bf16(af[eb][ks], bfr[h][ks][cb], a, 0, 0, 0);
                    fin[eb][cb] += av[eb] * a;
                }
        }
        // epilogue: + bias + residual
#pragma unroll
        for (int eb = 0; eb < 2; eb++)
#pragma unroll
            for (int cb = 0; cb < 2; cb++) {
                const int i = w * 32 + cb * 16 + (lane & 15);
#pragma unroll
                for (int r = 0; r < 4; r++) {
                    const int e = e0 + t * 32 + eb * 16 + (lane >> 4) * 4 + r;
                    const size_t off = (size_t)e * 128 + i;
                    out[off] = fin[eb][cb][r] + bias_r[cb] + bf2f(xbf[off]);
                }
            }
    }
}

extern "C" void kernel_launch(void* const* d_in, const int* in_sizes, int n_in,
                              void* d_out, int out_size, void* d_ws, size_t ws_size,
                              hipStream_t stream) {
    const float* x      = (const float*)d_in[0];
    const int*   ei_raw = (const int*)d_in[1];
    const float* att    = (const float*)d_in[2];
    const float* W      = (const float*)d_in[3];
    const float* b      = (const float*)d_in[4];
    float* out = (float*)d_out;

    char* ws = (char*)d_ws;
    float*    uv      = (float*)(ws);                     // N*8 f32   = 12.8 MB
    float*    p       = (float*)(ws + 12800000);          // E*4 f32   =  6.4 MB
    float*    denom   = (float*)(ws + 19200000);          // N*4 f32   =  6.4 MB
    ushort_t* wbf     = (ushort_t*)(ws + 32000000);       // 128 KB
    int*      flag    = (int*)(ws + 32200000);            // 4 B
    int*      ei32    = (int*)(ws + 32200064);            // 3.2 MB
    ushort_t* xbf     = (ushort_t*)(ws + 35400192);       // N*128 bf16 = 102.4 MB

    hipMemsetAsync(denom, 0, (size_t)NN * 4 * sizeof(float), stream);
    k_detect<<<1, 64, 0, stream>>>(ei_raw, flag);
    k_cvt_idx<<<2 * NE / 256, 256, 0, stream>>>(ei_raw, flag, ei32);
    k_wcvt<<<256, 256, 0, stream>>>(W, wbf);
    k_uv_cvt<<<2048, 256, 0, stream>>>(x, att, xbf, uv);
    k_edge<<<(NE + 255) / 256, 256, 0, stream>>>(ei32, uv, p, denom);
    k_gemm<<<NE / 128, 256, 0, stream>>>(xbf, ei32, p, denom, wbf, b, out);
}

// Round 6
// 285.143 us; speedup vs baseline: 1.5312x; 1.0594x over previous
//
#include <hip/hip_runtime.h>

#define NN 400000
#define NE 400000

typedef __attribute__((ext_vector_type(4))) float f32x4;
typedef __attribute__((ext_vector_type(8))) short s16x8;
typedef unsigned short ushort_t;

__device__ __forceinline__ ushort_t f2bf(float f) {
    union { float f; unsigned int u; } c;
    c.f = f;
    unsigned int u = c.u;
    u = u + 0x7fffu + ((u >> 16) & 1u);
    return (ushort_t)(u >> 16);
}
__device__ __forceinline__ float bf2f(ushort_t v) {
    union { unsigned int u; float f; } c;
    c.u = ((unsigned int)v) << 16;
    return c.f;
}

// --- detect whether edge_index arrived as int64 (odd 32-bit words all zero) ---
__global__ void k_detect(const int* __restrict__ ei_raw, int* __restrict__ flag) {
    if (threadIdx.x == 0 && blockIdx.x == 0) {
        int is64 = 1;
        for (int i = 0; i < 64; i++)
            if (ei_raw[2 * i + 1] != 0) { is64 = 0; break; }
        flag[0] = is64;
    }
}

__global__ void k_cvt_idx(const int* __restrict__ ei_raw, const int* __restrict__ flag,
                          int* __restrict__ ei32) {
    const int i = blockIdx.x * 256 + threadIdx.x;
    const int f = flag[0];
    ei32[i] = f ? ei_raw[2 * i] : ei_raw[i];
}

// --- W [128,512] f32 -> bf16, plain row-major ---
__global__ void k_wcvt(const float* __restrict__ W, ushort_t* __restrict__ wbf) {
    const int i = blockIdx.x * 256 + threadIdx.x;
    wbf[i] = f2bf(W[i]);
}

// --- fused: per-node u,v scores + x -> bf16 conversion (unchanged) ---
__global__ void k_uv_cvt(const float* __restrict__ x, const float* __restrict__ att,
                         ushort_t* __restrict__ xbf, float* __restrict__ uv) {
    const int lane = threadIdx.x & 63;
    const int wid = threadIdx.x >> 6;
    const int g = lane & 15;
    const int ns = lane >> 4;

    float areg[8][8];
#pragma unroll
    for (int h = 0; h < 4; h++) {
        const f32x4 fa = *(const f32x4*)(att + h * 256 + g * 8);
        const f32x4 fb = *(const f32x4*)(att + h * 256 + g * 8 + 4);
        const f32x4 ba = *(const f32x4*)(att + h * 256 + 128 + g * 8);
        const f32x4 bb = *(const f32x4*)(att + h * 256 + 128 + g * 8 + 4);
#pragma unroll
        for (int m = 0; m < 4; m++) {
            areg[h][m] = fa[m];     areg[h][4 + m] = fb[m];
            areg[4 + h][m] = ba[m]; areg[4 + h][4 + m] = bb[m];
        }
    }

    for (int tile = blockIdx.x; tile < NN / 32; tile += gridDim.x) {
        const int nb = tile * 32 + wid * 8 + ns;
#pragma unroll
        for (int t = 0; t < 2; t++) {
            const int n = nb + t * 4;
            const f32x4 xa = *(const f32x4*)(x + (size_t)n * 128 + g * 8);
            const f32x4 xb = *(const f32x4*)(x + (size_t)n * 128 + g * 8 + 4);
            s16x8 pk;
#pragma unroll
            for (int m = 0; m < 4; m++) { pk[m] = (short)f2bf(xa[m]); pk[4 + m] = (short)f2bf(xb[m]); }
            *(s16x8*)(xbf + (size_t)n * 128 + g * 8) = pk;
            float r[8];
#pragma unroll
            for (int v = 0; v < 8; v++) {
                float s = 0.f;
#pragma unroll
                for (int m = 0; m < 4; m++) s += xa[m] * areg[v][m];
#pragma unroll
                for (int m = 0; m < 4; m++) s += xb[m] * areg[v][4 + m];
                r[v] = s;
            }
#pragma unroll
            for (int mask = 1; mask <= 4; mask <<= 1)
#pragma unroll
                for (int v = 0; v < 8; v++) r[v] += __shfl_xor(r[v], mask, 64);
            const int gv = g & 7;
            float s = r[0];
#pragma unroll
            for (int v = 1; v < 8; v++) s = (gv == v) ? r[v] : s;
            s += __shfl_xor(s, 8, 64);
            if (g < 8) uv[(size_t)n * 8 + g] = s;
        }
    }
}

// --- per-edge: leaky_relu -> head softmax -> p=exp(score), atomic denom ---
__global__ void k_edge(const int* __restrict__ ei, const float* __restrict__ uv,
                       float* __restrict__ p, float* __restrict__ denom) {
    const int e = blockIdx.x * 256 + threadIdx.x;
    if (e >= NE) return;
    const int row = ei[e];
    const int col = ei[NE + e];
    const f32x4 u = *(const f32x4*)(uv + (size_t)row * 8);
    const f32x4 v = *(const f32x4*)(uv + (size_t)col * 8 + 4);
    float s[4];
    float mx = -1e30f;
#pragma unroll
    for (int h = 0; h < 4; h++) {
        float t = u[h] + v[h];
        t = t > 0.f ? t : 0.01f * t;
        s[h] = t;
        mx = fmaxf(mx, t);
    }
    float ex[4], sum = 0.f;
#pragma unroll
    for (int h = 0; h < 4; h++) { ex[h] = __expf(s[h] - mx); sum += ex[h]; }
    const float inv = 1.f / sum;
    f32x4 pv;
#pragma unroll
    for (int h = 0; h < 4; h++) pv[h] = __expf(ex[h] * inv);
    *(f32x4*)(p + (size_t)e * 4) = pv;
#pragma unroll
    for (int h = 0; h < 4; h++) atomicAdd(denom + (size_t)row * 4 + h, pv[h]);
}

// --- hybrid head-split GEMM, v3.
//     Block: 128 edges x 128 cols, 4 waves; wave owns 32 cols.
//     A staged ONCE via async global_load_lds (linear LDS dest, swizzle encoded
//     in the per-lane GLOBAL source address: slot = chunk ^ (row&15)).
//     B (4 heads x K=128 x 32 cols) in 128 VGPRs per wave, loaded once —
//     __launch_bounds__(256,2) raises the VGPR cap so B is NOT rematerialized.
//     alpha computed inline into 2KB LDS. ONE barrier total. ---
__global__ __launch_bounds__(256, 2) void k_gemm(
    const ushort_t* __restrict__ xbf, const int* __restrict__ ei,
    const float* __restrict__ p, const float* __restrict__ denom,
    const ushort_t* __restrict__ wbf, const float* __restrict__ bias,
    float* __restrict__ out)
{
    __shared__ __align__(16) ushort_t Asm[128 * 128];  // [e][slot] bf16; slot = chunk ^ (e&15)
    __shared__ __align__(16) float alp_s[4][128];

    const int tid = threadIdx.x;
    const int lane = tid & 63;
    const int w = tid >> 6;          // wave: cols w*32..w*32+32
    const int e0 = blockIdx.x * 128;

    // A stage: 8 async global_load_lds per thread. Issue i of wave w covers
    // rows w*32 + i*4 .. +4 (1KB LDS, wave-uniform base; HW adds lane*16).
    // Lane l: row rr = w*32 + i*4 + (l>>4), slot s = l&15, logical chunk
    // c = s ^ (rr&15)  -> source xbf[col(rr)]*128 + c*8 elements.
    {
#pragma unroll
        for (int i = 0; i < 8; i++) {
            const int rr = w * 32 + i * 4 + (lane >> 4);
            const int col = ei[NE + e0 + rr];
            const int c = (lane & 15) ^ (rr & 15);
            const ushort_t* src = xbf + (size_t)col * 128 + c * 8;
            __builtin_amdgcn_global_load_lds(
                (const __attribute__((address_space(1))) unsigned int*)src,
                (__attribute__((address_space(3))) unsigned int*)((char*)Asm + w * 8192 + i * 1024),
                16, 0, 0);
        }
    }
    // alpha inline: alp_s[h][e] = p[e,h] / denom[row[e],h]
    if (tid < 128) {
        const int e = e0 + tid;
        const int row = ei[e];
        const f32x4 pv = *(const f32x4*)(p + (size_t)e * 4);
        const f32x4 dv = *(const f32x4*)(denom + (size_t)row * 4);
#pragma unroll
        for (int h = 0; h < 4; h++) alp_s[h][tid] = pv[h] / dv[h];
    }
    // B fragments in registers: bfr[h][ks][cb]; lane row i=(lane&15), k8 group (lane>>4)
    s16x8 bfr[4][4][2];
#pragma unroll
    for (int cb = 0; cb < 2; cb++) {
        const ushort_t* bbase = wbf + (size_t)(w * 32 + cb * 16 + (lane & 15)) * 512 + (lane >> 4) * 8;
#pragma unroll
        for (int h = 0; h < 4; h++)
#pragma unroll
            for (int ks = 0; ks < 4; ks++)
                bfr[h][ks][cb] = *(const s16x8*)(bbase + h * 128 + ks * 32);
    }
    float bias_r[2];
#pragma unroll
    for (int cb = 0; cb < 2; cb++) bias_r[cb] = bias[w * 32 + cb * 16 + (lane & 15)];

    __syncthreads();   // drains vmcnt (global_load_lds) + lds writes; no further barriers

    const f32x4 zero = {0.f, 0.f, 0.f, 0.f};

#pragma unroll 1
    for (int t = 0; t < 4; t++) {
        // A fragments from LDS (swizzled read matches source permutation)
        s16x8 af[2][4];
#pragma unroll
        for (int eb = 0; eb < 2; eb++) {
            const int rr = t * 32 + eb * 16 + (lane & 15);
#pragma unroll
            for (int ks = 0; ks < 4; ks++) {
                const int byte = rr * 256 + ((ks * 64 + (lane >> 4) * 16) ^ ((rr & 15) << 4));
                af[eb][ks] = *(const s16x8*)((const char*)Asm + byte);
            }
        }
        f32x4 fin[2][2];
#pragma unroll
        for (int eb = 0; eb < 2; eb++)
#pragma unroll
            for (int cb = 0; cb < 2; cb++) fin[eb][cb] = zero;

#pragma unroll
        for (int h = 0; h < 4; h++) {
            f32x4 av[2];
#pragma unroll
            for (int eb = 0; eb < 2; eb++)
                av[eb] = *(const f32x4*)&alp_s[h][t * 32 + eb * 16 + (lane >> 4) * 4];
#pragma unroll
            for (int eb = 0; eb < 2; eb++)
#pragma unroll
                for (int cb = 0; cb < 2; cb++) {
                    f32x4 a = __builtin_amdgcn_mfma_f32_16x16x32_bf16(af[eb][0], bfr[h][0][cb], zero, 0, 0, 0);
#pragma unroll
                    for (int ks = 1; ks < 4; ks++)
                        a = __builtin_amdgcn_mfma_f32_16x16x32_bf16(af[eb][ks], bfr[h][ks][cb], a, 0, 0, 0);
                    fin[eb][cb] += av[eb] * a;
                }
        }
        // epilogue: + bias + residual
#pragma unroll
        for (int eb = 0; eb < 2; eb++)
#pragma unroll
            for (int cb = 0; cb < 2; cb++) {
                const int i = w * 32 + cb * 16 + (lane & 15);
#pragma unroll
                for (int r = 0; r < 4; r++) {
                    const int e = e0 + t * 32 + eb * 16 + (lane >> 4) * 4 + r;
                    const size_t off = (size_t)e * 128 + i;
                    out[off] = fin[eb][cb][r] + bias_r[cb] + bf2f(xbf[off]);
                }
            }
    }
}

extern "C" void kernel_launch(void* const* d_in, const int* in_sizes, int n_in,
                              void* d_out, int out_size, void* d_ws, size_t ws_size,
                              hipStream_t stream) {
    const float* x      = (const float*)d_in[0];
    const int*   ei_raw = (const int*)d_in[1];
    const float* att    = (const float*)d_in[2];
    const float* W      = (const float*)d_in[3];
    const float* b      = (const float*)d_in[4];
    float* out = (float*)d_out;

    char* ws = (char*)d_ws;
    float*    uv      = (float*)(ws);                     // N*8 f32   = 12.8 MB
    float*    p       = (float*)(ws + 12800000);          // E*4 f32   =  6.4 MB
    float*    denom   = (float*)(ws + 19200000);          // N*4 f32   =  6.4 MB
    ushort_t* wbf     = (ushort_t*)(ws + 32000000);       // 128 KB
    int*      flag    = (int*)(ws + 32200000);            // 4 B
    int*      ei32    = (int*)(ws + 32200064);            // 3.2 MB
    ushort_t* xbf     = (ushort_t*)(ws + 35400192);       // N*128 bf16 = 102.4 MB

    hipMemsetAsync(denom, 0, (size_t)NN * 4 * sizeof(float), stream);
    k_detect<<<1, 64, 0, stream>>>(ei_raw, flag);
    k_cvt_idx<<<2 * NE / 256, 256, 0, stream>>>(ei_raw, flag, ei32);
    k_wcvt<<<256, 256, 0, stream>>>(W, wbf);
    k_uv_cvt<<<2048, 256, 0, stream>>>(x, att, xbf, uv);
    k_edge<<<(NE + 255) / 256, 256, 0, stream>>>(ei32, uv, p, denom);
    k_gemm<<<NE / 128, 256, 0, stream>>>(xbf, ei32, p, denom, wbf, b, out);
}